// Round 3
// baseline (58.734 us; speedup 1.0000x reference)
//
#include <hip/hip_runtime.h>
#include <math.h>

// Problem constants (from reference setup_inputs)
#define BB 32
#define TT 2048
#define HH 1024

// Kernel 1: v[b,h] = sum_o dec[b,o] * W[o,h]   (v = dec @ W)
// grid (HH/64, BB/2) = (16,16) = 256 blocks (1 per CU); block 256 = 4 waves.
// Each block: 64 h's, 2 b's, all 1024 o's. Wave w owns o-quarter [w*256,+256).
// dec staged in LDS (wave-uniform broadcast reads); W rows read coalesced and
// REUSED across both b's -> total W traffic 64 MB (was 128 MB at 1 b/block).
__global__ __launch_bounds__(256)
void proj_vec_kernel(const float* __restrict__ dec,
                     const float* __restrict__ W,
                     float* __restrict__ v) {
    const int tid  = threadIdx.x;
    const int lane = tid & 63;
    const int wave = tid >> 6;            // o-quarter
    const int h0   = blockIdx.x * 64;
    const int b0   = blockIdx.y * 2;

    __shared__ float sdec[2][HH];         // 8 KB, contiguous with dec[b0..b0+1]
    {
        const float4* src = reinterpret_cast<const float4*>(dec + (size_t)b0 * HH);
        float4* dst = reinterpret_cast<float4*>(&sdec[0][0]);
        dst[tid]       = src[tid];
        dst[tid + 256] = src[tid + 256];
    }
    __syncthreads();

    const int o0 = wave * 256;
    const float* sd0 = &sdec[0][o0];
    const float* sd1 = &sdec[1][o0];
    const float* Wcol = W + (size_t)o0 * HH + h0 + lane;

    float a0 = 0.f, a1 = 0.f;
#pragma unroll 4
    for (int oo = 0; oo < 256; oo += 4) {
        float4 d0 = *reinterpret_cast<const float4*>(sd0 + oo);  // LDS broadcast
        float4 d1 = *reinterpret_cast<const float4*>(sd1 + oo);
        float w0 = Wcol[(size_t)(oo + 0) * HH];   // 256 B coalesced per wave
        float w1 = Wcol[(size_t)(oo + 1) * HH];
        float w2 = Wcol[(size_t)(oo + 2) * HH];
        float w3 = Wcol[(size_t)(oo + 3) * HH];
        a0 += d0.x * w0 + d0.y * w1 + d0.z * w2 + d0.w * w3;
        a1 += d1.x * w0 + d1.y * w1 + d1.z * w2 + d1.w * w3;
    }

    __shared__ float red[4][2][64];       // 2 KB
    red[wave][0][lane] = a0;
    red[wave][1][lane] = a1;
    __syncthreads();
    if (tid < 128) {
        const int b = tid >> 6;
        v[(size_t)(b0 + b) * HH + h0 + lane] =
            (red[0][b][lane] + red[1][b][lane]) +
            (red[2][b][lane] + red[3][b][lane]);
    }
}

// Kernel 2: energy[b,t] = enc[b,t,:] . v[b,:]
// grid (64, BB) = 2048 blocks; block 256 = 4 waves; 256 waves per b.
// Each wave: hoist v[b,:] into 4 float4 registers ONCE, then stream 8
// consecutive rows (32 KB of enc) doing pure e-loads + FMA + shfl-reduce.
__global__ __launch_bounds__(256)
void energy_kernel(const float* __restrict__ enc,
                   const float* __restrict__ v,
                   float* __restrict__ energy) {
    const int wave = threadIdx.x >> 6;
    const int lane = threadIdx.x & 63;
    const int b    = blockIdx.y;
    const int wid  = blockIdx.x * 4 + wave;      // 0..255 within this b
    const int t0   = wid * 8;                    // first of 8 rows

    const float4* v4 = reinterpret_cast<const float4*>(v + b * HH);
    const float4 w0 = v4[0 * 64 + lane];
    const float4 w1 = v4[1 * 64 + lane];
    const float4 w2 = v4[2 * 64 + lane];
    const float4 w3 = v4[3 * 64 + lane];

    const float4* ebase =
        reinterpret_cast<const float4*>(enc + ((size_t)b * TT + t0) * HH);

#pragma unroll 2
    for (int r = 0; r < 8; ++r) {
        const float4* e4 = ebase + (size_t)r * (HH / 4);
        float4 e0 = e4[0 * 64 + lane];
        float4 e1 = e4[1 * 64 + lane];
        float4 e2 = e4[2 * 64 + lane];
        float4 e3 = e4[3 * 64 + lane];
        float acc = e0.x * w0.x + e0.y * w0.y + e0.z * w0.z + e0.w * w0.w;
        acc += e1.x * w1.x + e1.y * w1.y + e1.z * w1.z + e1.w * w1.w;
        acc += e2.x * w2.x + e2.y * w2.y + e2.z * w2.z + e2.w * w2.w;
        acc += e3.x * w3.x + e3.y * w3.y + e3.z * w3.z + e3.w * w3.w;
#pragma unroll
        for (int off = 32; off > 0; off >>= 1) acc += __shfl_down(acc, off, 64);
        if (lane == 0) energy[b * TT + t0 + r] = acc;
    }
}

// Kernel 3: softmax over t for each b. One block (256 threads) per b.
__global__ __launch_bounds__(256)
void softmax_kernel(const float* __restrict__ energy,
                    float* __restrict__ out) {
    const int b   = blockIdx.x;
    const int tid = threadIdx.x;
    const float* e = energy + b * TT;
    float vals[8];
    float m = -INFINITY;
#pragma unroll
    for (int k = 0; k < 8; ++k) {
        vals[k] = e[tid + k * 256];
        m = fmaxf(m, vals[k]);
    }
    __shared__ float redm[4];
    __shared__ float reds[4];
#pragma unroll
    for (int off = 32; off > 0; off >>= 1) m = fmaxf(m, __shfl_xor(m, off, 64));
    if ((tid & 63) == 0) redm[tid >> 6] = m;
    __syncthreads();
    m = fmaxf(fmaxf(redm[0], redm[1]), fmaxf(redm[2], redm[3]));

    float s = 0.f;
#pragma unroll
    for (int k = 0; k < 8; ++k) {
        vals[k] = __expf(vals[k] - m);
        s += vals[k];
    }
#pragma unroll
    for (int off = 32; off > 0; off >>= 1) s += __shfl_xor(s, off, 64);
    if ((tid & 63) == 0) reds[tid >> 6] = s;
    __syncthreads();
    s = reds[0] + reds[1] + reds[2] + reds[3];
    const float inv = 1.0f / s;
#pragma unroll
    for (int k = 0; k < 8; ++k) out[b * TT + tid + k * 256] = vals[k] * inv;
}

extern "C" void kernel_launch(void* const* d_in, const int* in_sizes, int n_in,
                              void* d_out, int out_size, void* d_ws, size_t ws_size,
                              hipStream_t stream) {
    const float* dec = (const float*)d_in[0];   // [B,H]
    const float* enc = (const float*)d_in[1];   // [B,T,H]
    const float* W   = (const float*)d_in[2];   // [H,H] (row = o, col = h)
    // d_in[3] (bias) is intentionally unused: it contributes a per-b constant
    // to the energies, which softmax's shift invariance cancels exactly.
    float* out = (float*)d_out;                 // [B,T,1] f32

    float* v      = (float*)d_ws;               // BB*HH floats = 128 KiB
    float* energy = v + BB * HH;                // BB*TT floats = 256 KiB

    proj_vec_kernel<<<dim3(HH / 64, BB / 2), 256, 0, stream>>>(dec, W, v);
    energy_kernel<<<dim3(64, BB), 256, 0, stream>>>(enc, v, energy);
    softmax_kernel<<<BB, 256, 0, stream>>>(energy, out);
}